// Round 6
// baseline (1098.373 us; speedup 1.0000x reference)
//
#include <hip/hip_runtime.h>

// Problem constants
constexpr int Bz = 512;   // batch
constexpr int Tz = 256;   // seq len
constexpr int Hz = 256;   // hidden
constexpr int Pz = 14;    // predict dim
constexpr int GB = 32;    // batch groups
constexpr int GS = 4;     // hidden slices per group (R15: was 8)
constexpr int BT = 16;    // batch per group (512/32)
constexpr int KP = 264;   // LDS h row stride (shorts)
constexpr int XS = 260;   // x LDS row stride (floats)
constexpr int THR = 512;  // threads per block (R15: was 256)

typedef short s8v __attribute__((ext_vector_type(8)));
typedef float f4v __attribute__((ext_vector_type(4)));
typedef unsigned long long u64;

__device__ __forceinline__ short f2bf(float f) {
  unsigned u = __float_as_uint(f);
  u = (u + 0x7fffu + ((u >> 16) & 1u)) >> 16;   // RNE
  return (short)u;
}
__device__ __forceinline__ float bf2f(short s) {
  return __uint_as_float(((unsigned)(unsigned short)s) << 16);
}
// Fast gates (R11/R14-proven numerics, same absmax as libm path)
__device__ __forceinline__ float sigm(float v) {
  return __builtin_amdgcn_rcpf(1.0f + __builtin_amdgcn_exp2f(-1.442695041f * v));
}
__device__ __forceinline__ float tanh_f(float v) {
  return 1.0f - 2.0f * __builtin_amdgcn_rcpf(__builtin_amdgcn_exp2f(2.885390082f * v) + 1.0f);
}

__device__ __forceinline__ u64 llc_load64(const u64* p) {
  return __hip_atomic_load(p, __ATOMIC_RELAXED, __HIP_MEMORY_SCOPE_AGENT);
}
__device__ __forceinline__ unsigned llc_load32(const unsigned* p) {
  return __hip_atomic_load(p, __ATOMIC_RELAXED, __HIP_MEMORY_SCOPE_AGENT);
}
__device__ __forceinline__ void llc_store32(unsigned* p, unsigned v) {
  __hip_atomic_store(p, v, __ATOMIC_RELAXED, __HIP_MEMORY_SCOPE_AGENT);
}
__device__ __forceinline__ void llc_store64(u64* p, u64 v) {
  __hip_atomic_store(p, v, __ATOMIC_RELAXED, __HIP_MEMORY_SCOPE_AGENT);
}

// R15 = R14 (727us proven: combined u64 h-word, wave0 poll + barrier, tid0
// publisher, fast gates) with the group shrunk from 8 blocks x 256 thr to
// 4 blocks x 512 thr:
//   - straggler max over 4 producers instead of 8
//   - 4 flag publishes/group/step instead of 8 (less flag-line contention)
//   - 128 blocks / 128 polling waves machine-wide instead of 256
// Per-thread work, register budget (Wf 192 VGPR), exchange volume, parities,
// and the safety argument are IDENTICAL to R14. Only the slot decode changes:
//   slot slw = sl*8 + w (sl in 0..3, w in 0..7), global array [32][512][4] u32
//   kpos = slw*8 + q*2 + j  <->  k_true = sl*64 + w*4 + q + 32*j
__global__ void __launch_bounds__(512, 1)
lstm2(const float* __restrict__ x,
      const float* __restrict__ w_ih0, const float* __restrict__ w_hh0,
      const float* __restrict__ b_ih0, const float* __restrict__ b_hh0,
      const float* __restrict__ w_ih1, const float* __restrict__ w_hh1,
      const float* __restrict__ b_ih1, const float* __restrict__ b_hh1,
      const float* __restrict__ w_lin, const float* __restrict__ b_lin,
      float* __restrict__ out,
      u64* __restrict__ hg, unsigned* __restrict__ flags)
{
  const int blk  = blockIdx.x;
  const int g    = blk >> 2;      // batch group (32)
  const int sl   = blk & 3;       // hidden slice (4)
  const int tid  = threadIdx.x;
  const int w    = tid >> 6;      // wave 0..7
  const int lane = tid & 63;
  const int q    = lane >> 4;
  const int l15  = lane & 15;     // batch within group
  const int gbase = g * BT;

  extern __shared__ char smem_raw[];
  short* h0s = (short*)smem_raw;          // [BT][KP] staged h0[s-1], kpos order
  short* h1s = h0s + BT * KP;             // [BT][KP] staged h1[s-2]
  float* xls = (float*)(h1s + BT * KP);   // [BT][XS] x preload
  float* wls = xls + BT * XS;             // [Pz][256] w_lin permuted to kpos order

  // ---- one-time: weights -> register A-fragments (permuted k gather) ----
  // B-frag elem j at kpos = kt*32 + q*8 + j; decode x = kt*4+q (slot slw'),
  // k_true = (x>>3)*64 + (x&7)*4 + (j>>1) + 32*(j&1)   [R15 slot decode]
  s8v Wf[3][2][8];   // [mat: hh0, ih1, hh1][mti][kt]
  {
    const float* wsrc[3] = {w_hh0, w_ih1, w_hh1};
    #pragma unroll
    for (int mat = 0; mat < 3; ++mat) {
      #pragma unroll
      for (int mti = 0; mti < 2; ++mti) {
        int rr = (w + mti * 8) * 16 + l15;          // A-row: rr = unit*4+gate
        int grow = (rr & 3) * Hz + sl * 64 + (rr >> 2);
        const float* p = wsrc[mat] + (size_t)grow * Hz;
        #pragma unroll
        for (int kt = 0; kt < 8; ++kt) {
          s8v f;
          #pragma unroll
          for (int j = 0; j < 8; ++j) {
            int xk = kt * 4 + q;
            int ktrue = (xk >> 3) * 64 + (xk & 7) * 4 + (j >> 1) + 32 * (j & 1);
            f[j] = f2bf(p[ktrue]);
          }
          Wf[mat][mti][kt] = f;
        }
      }
    }
  }
  // per-lane epilogue constants: units uA = sl*64 + w*4+q, uB = uA+32
  const int uA = sl * 64 + w * 4 + q, uB = uA + 32;
  float wihA[4], wihB[4], b0A[4], b0B[4], b1A[4], b1B[4];
  #pragma unroll
  for (int r = 0; r < 4; ++r) {
    int ga_ = r * Hz + uA;
    int gb_ = r * Hz + uB;
    wihA[r] = w_ih0[ga_];              wihB[r] = w_ih0[gb_];
    b0A[r]  = b_ih0[ga_] + b_hh0[ga_]; b0B[r]  = b_ih0[gb_] + b_hh0[gb_];
    b1A[r]  = b_ih1[ga_] + b_hh1[ga_]; b1B[r]  = b_ih1[gb_] + b_hh1[gb_];
  }
  float c0A = 0.f, c0B = 0.f, c1A = 0.f, c1B = 0.f;   // cell states in VGPRs

  // ---- preload x (this group's 16 batches) and permuted w_lin (head) ----
  for (int i = tid; i < BT * (Tz / 4); i += THR) {
    int b = i >> 6, c4 = i & 63;
    f4v v = *(const f4v*)(x + (size_t)(gbase + b) * Tz + c4 * 4);
    *(f4v*)(xls + b * XS + c4 * 4) = v;
  }
  if (sl == 0) {
    for (int i = tid; i < Pz * Hz; i += THR) {
      int p = i >> 8, kpos = i & 255;
      int slw2 = kpos >> 3, inner = kpos & 7;
      int q2 = inner >> 1, j2 = inner & 1;
      int ktrue = (slw2 >> 3) * 64 + (slw2 & 7) * 4 + q2 + 32 * j2;
      wls[i] = w_lin[p * Hz + ktrue];
    }
  }

  const unsigned* myflags = flags + g * 32 + (lane & 3);  // group's 4 flags
  unsigned* myflag = flags + g * 32 + sl;

  for (int s = 0; s <= Tz; ++s) {
    // ---- A: wave0 polls: all 4 producers completed step s-1; barrier gates rest ----
    if (w == 0) {
      const unsigned expd = (unsigned)s;
      unsigned f = llc_load32(myflags);
      while (__ballot(f >= expd) != ~0ull) {
        __builtin_amdgcn_s_sleep(1);
        f = llc_load32(myflags);
      }
    }
    __syncthreads();   // barrier A: poll verdict gates all waves' stage loads

    // ---- B: stage combined words from parity (s+1)&1 = (s-1)&1 ----
    // word (slw, b, q) = lo32: h0 pair (uA,uB) | hi32: h1 pair, iter s-1
    {
      const u64* sp = hg + (size_t)((s + 1) & 1) * 65536;
      u64 r[4];
      #pragma unroll
      for (int k = 0; k < 2; ++k) {
        int i = tid + k * THR;
        int c = i & 1, b = (i >> 1) & 15, slw = i >> 5;
        size_t gi = ((size_t)slw * Bz + gbase + b) * 4 + 2 * c;
        r[2 * k]     = llc_load64(sp + gi);
        r[2 * k + 1] = llc_load64(sp + gi + 1);
      }
      #pragma unroll
      for (int k = 0; k < 2; ++k) {
        int i = tid + k * THR;
        int c = i & 1, b = (i >> 1) & 15, slw = i >> 5;
        u64 lo = r[2 * k], hi = r[2 * k + 1];
        *(u64*)(h0s + b * KP + slw * 8 + c * 4) =
            (u64)(unsigned)lo | ((u64)(unsigned)hi << 32);
        *(u64*)(h1s + b * KP + slw * 8 + c * 4) =
            (lo >> 32) | ((hi >> 32) << 32);
      }
    }
    __syncthreads();   // sync1: staged LDS visible

    // ---- C: fused MFMA (L0: 16, L1: 32); weights from regs; 16 b128 reads ----
    f4v a0A = {0.f,0.f,0.f,0.f}, a0B = {0.f,0.f,0.f,0.f};
    f4v a1A = {0.f,0.f,0.f,0.f}, a1B = {0.f,0.f,0.f,0.f};
    const short* H0f = h0s + l15 * KP + q * 8;
    const short* H1f = h1s + l15 * KP + q * 8;
    #pragma unroll
    for (int kt = 0; kt < 8; ++kt) {
      s8v h0v = *(const s8v*)(H0f + kt * 32);
      s8v h1v = *(const s8v*)(H1f + kt * 32);
      a0A = __builtin_amdgcn_mfma_f32_16x16x32_bf16(Wf[0][0][kt], h0v, a0A, 0, 0, 0);
      a0B = __builtin_amdgcn_mfma_f32_16x16x32_bf16(Wf[0][1][kt], h0v, a0B, 0, 0, 0);
      a1A = __builtin_amdgcn_mfma_f32_16x16x32_bf16(Wf[1][0][kt], h0v, a1A, 0, 0, 0);
      a1B = __builtin_amdgcn_mfma_f32_16x16x32_bf16(Wf[1][1][kt], h0v, a1B, 0, 0, 0);
      a1A = __builtin_amdgcn_mfma_f32_16x16x32_bf16(Wf[2][0][kt], h1v, a1A, 0, 0, 0);
      a1B = __builtin_amdgcn_mfma_f32_16x16x32_bf16(Wf[2][1][kt], h1v, a1B, 0, 0, 0);
    }

    // ---- D: in-register epilogues -> one packed u32 per layer ----
    unsigned pk0 = 0, pk1 = 0;
    if (s < Tz) {
      float xv = xls[l15 * XS + s];
      float iA = sigm  (a0A[0] + xv * wihA[0] + b0A[0]);
      float fA = sigm  (a0A[1] + xv * wihA[1] + b0A[1]);
      float gA = tanh_f(a0A[2] + xv * wihA[2] + b0A[2]);
      float oA = sigm  (a0A[3] + xv * wihA[3] + b0A[3]);
      c0A = fA * c0A + iA * gA;
      float iB = sigm  (a0B[0] + xv * wihB[0] + b0B[0]);
      float fB = sigm  (a0B[1] + xv * wihB[1] + b0B[1]);
      float gB = tanh_f(a0B[2] + xv * wihB[2] + b0B[2]);
      float oB = sigm  (a0B[3] + xv * wihB[3] + b0B[3]);
      c0B = fB * c0B + iB * gB;
      pk0 = (unsigned)(unsigned short)f2bf(oA * tanh_f(c0A))
          | ((unsigned)(unsigned short)f2bf(oB * tanh_f(c0B)) << 16);
    }
    if (s >= 1) {
      float iA = sigm  (a1A[0] + b1A[0]);
      float fA = sigm  (a1A[1] + b1A[1]);
      float gA = tanh_f(a1A[2] + b1A[2]);
      float oA = sigm  (a1A[3] + b1A[3]);
      c1A = fA * c1A + iA * gA;
      float iB = sigm  (a1B[0] + b1B[0]);
      float fB = sigm  (a1B[1] + b1B[1]);
      float gB = tanh_f(a1B[2] + b1B[2]);
      float oB = sigm  (a1B[3] + b1B[3]);
      c1B = fB * c1B + iB * gB;
      pk1 = (unsigned)(unsigned short)f2bf(oA * tanh_f(c1A))
          | ((unsigned)(unsigned short)f2bf(oB * tanh_f(c1B)) << 16);
    }

    // ---- E: ONE combined coalesced store (unconditional) ----
    // pk1=0 at s=0 is the true h1[-1]=0; pk0=0 at s=Tz is never read.
    {
      size_t base = (size_t)(sl * 8 + w) * 2048 + (size_t)(gbase + l15) * 4 + q;
      llc_store64(hg + (size_t)(s & 1) * 65536 + base,
                  (u64)pk0 | ((u64)pk1 << 32));
    }

    // ---- F: drain (per-wave vmcnt(0) inside __syncthreads) + publish ----
    __syncthreads();
    if (tid == 0)
      llc_store32(myflag, (unsigned)(s + 1));
  }

  // ---- final head (sl==0 blocks): out = h1[Tz-1] @ w_lin^T + b_lin ----
  // h1[Tz-1] = hi32 halves of combined words written at iter Tz, parity 0.
  if (sl == 0) {
    {
      const unsigned expd = (unsigned)(Tz + 1);
      unsigned f = llc_load32(myflags);
      while (__ballot(f >= expd) != ~0ull) {
        __builtin_amdgcn_s_sleep(1);
        f = llc_load32(myflags);
      }
    }
    const u64* sp = hg + (size_t)(Tz & 1) * 65536;   // parity 0
    for (int k = 0; k < 2; ++k) {
      int i = tid + k * THR;
      int c = i & 1, b = (i >> 1) & 15, slw = i >> 5;
      size_t gi = ((size_t)slw * Bz + gbase + b) * 4 + 2 * c;
      u64 lo = llc_load64(sp + gi);
      u64 hi = llc_load64(sp + gi + 1);
      *(u64*)(h0s + b * KP + slw * 8 + c * 4) = (lo >> 32) | ((hi >> 32) << 32);
    }
    __syncthreads();
    for (int i = tid; i < BT * Pz; i += THR) {
      int b = i / Pz, p = i - b * Pz;
      const float* wr = wls + p * Hz;
      float acc = b_lin[p];
      for (int kk = 0; kk < Hz; ++kk)
        acc += bf2f(h0s[b * KP + kk]) * wr[kk];   // both in kpos order
      out[(gbase + b) * Pz + p] = acc;
    }
  }
}

extern "C" void kernel_launch(void* const* d_in, const int* in_sizes, int n_in,
                              void* d_out, int out_size, void* d_ws, size_t ws_size,
                              hipStream_t stream) {
  const float* x     = (const float*)d_in[0];
  const float* w_ih0 = (const float*)d_in[1];
  const float* w_hh0 = (const float*)d_in[2];
  const float* b_ih0 = (const float*)d_in[3];
  const float* b_hh0 = (const float*)d_in[4];
  const float* w_ih1 = (const float*)d_in[5];
  const float* w_hh1 = (const float*)d_in[6];
  const float* b_ih1 = (const float*)d_in[7];
  const float* b_hh1 = (const float*)d_in[8];
  const float* w_lin = (const float*)d_in[9];
  const float* b_lin = (const float*)d_in[10];
  float* out = (float*)d_out;

  unsigned char* ws = (unsigned char*)d_ws;
  u64* hg         = (u64*)ws;                          // [2][65536] u64 (512 KB/parity)
  unsigned* flags = (unsigned*)(ws + (1 << 20));       // [32 groups][32] u32 (4 used)
  // memset(0): h data zeros (bf16 0x0000 = initial hidden state) + flags = 0
  hipMemsetAsync(d_ws, 0, (1 << 20) + 4096, stream);

  size_t lds_bytes = (size_t)(2 * BT) * KP * 2     // h staging
                   + (size_t)(BT * XS) * 4         // x preload
                   + (size_t)(Pz * Hz) * 4;        // permuted w_lin (head)
  hipFuncSetAttribute((const void*)lstm2,
                      hipFuncAttributeMaxDynamicSharedMemorySize, (int)lds_bytes);
  lstm2<<<GB * GS, THR, lds_bytes, stream>>>(x, w_ih0, w_hh0, b_ih0, b_hh0,
                                             w_ih1, w_hh1, b_ih1, b_hh1,
                                             w_lin, b_lin, out, hg, flags);
}

// Round 7
// 1087.003 us; speedup vs baseline: 1.0105x; 1.0105x over previous
//
#include <hip/hip_runtime.h>

// Problem constants
constexpr int Bz = 512;   // batch
constexpr int Tz = 256;   // seq len
constexpr int Hz = 256;   // hidden
constexpr int Pz = 14;    // predict dim
constexpr int GB = 32;    // batch groups
constexpr int GS = 4;     // hidden slices per group
constexpr int BT = 16;    // batch per group (512/32)
constexpr int KP = 264;   // LDS h row stride (shorts)
constexpr int XS = 260;   // x LDS row stride (floats)
constexpr int THR = 512;  // threads per block

typedef short s8v __attribute__((ext_vector_type(8)));
typedef float f4v __attribute__((ext_vector_type(4)));
typedef unsigned long long u64;

__device__ __forceinline__ short f2bf(float f) {
  unsigned u = __float_as_uint(f);
  u = (u + 0x7fffu + ((u >> 16) & 1u)) >> 16;   // RNE
  return (short)u;
}
__device__ __forceinline__ float bf2f(short s) {
  return __uint_as_float(((unsigned)(unsigned short)s) << 16);
}
// Fast gates (R11/R14-proven numerics, same absmax as libm path)
__device__ __forceinline__ float sigm(float v) {
  return __builtin_amdgcn_rcpf(1.0f + __builtin_amdgcn_exp2f(-1.442695041f * v));
}
__device__ __forceinline__ float tanh_f(float v) {
  return 1.0f - 2.0f * __builtin_amdgcn_rcpf(__builtin_amdgcn_exp2f(2.885390082f * v) + 1.0f);
}

__device__ __forceinline__ u64 llc_load64(const u64* p) {
  return __hip_atomic_load(p, __ATOMIC_RELAXED, __HIP_MEMORY_SCOPE_AGENT);
}
__device__ __forceinline__ unsigned llc_load32(const unsigned* p) {
  return __hip_atomic_load(p, __ATOMIC_RELAXED, __HIP_MEMORY_SCOPE_AGENT);
}
__device__ __forceinline__ void llc_store32(unsigned* p, unsigned v) {
  __hip_atomic_store(p, v, __ATOMIC_RELAXED, __HIP_MEMORY_SCOPE_AGENT);
}
__device__ __forceinline__ void llc_store64(u64* p, u64 v) {
  __hip_atomic_store(p, v, __ATOMIC_RELAXED, __HIP_MEMORY_SCOPE_AGENT);
}

// R16 = R15 with the ONLY change being __launch_bounds__(512, 2).
// R15's regression was a register-budget failure, not a structural one:
// launch_bounds(512,1) -> k = w/2 = 0.5 blocks/CU (ill-formed) -> compiler
// fell back to a 128-VGPR target -> Wf (192 VGPR) spilled to scratch ->
// re-read every step (WRITE_SIZE +64MB, dur 727->1098). With w=2:
// k = 1 block/CU, VGPR cap = 512/2 = 256 = what the 8-wave block needs.
// Structure (proven protocol from R14 @ 727us, reshaped to 4 producers):
//   - 4 blocks x 512 thr per group: straggler max-of-4, 4 publishes/step,
//     128 polling waves machine-wide (R15's FETCH 316MB confirmed the
//     traffic halving).
//   - combined u64 h-word (h0[s] | h1[s-1]) at parity s&1
//   - wave0-only flag poll + barrier; tid0 publish after __syncthreads
//     (per-wave vmcnt(0) drain inside, R5-proven)
//   - slot decode: slw = sl*8 + w; kpos = slw*8 + q*2 + j <->
//     k_true = sl*64 + w*4 + q + 32*j
__global__ void __launch_bounds__(512, 2)
lstm2(const float* __restrict__ x,
      const float* __restrict__ w_ih0, const float* __restrict__ w_hh0,
      const float* __restrict__ b_ih0, const float* __restrict__ b_hh0,
      const float* __restrict__ w_ih1, const float* __restrict__ w_hh1,
      const float* __restrict__ b_ih1, const float* __restrict__ b_hh1,
      const float* __restrict__ w_lin, const float* __restrict__ b_lin,
      float* __restrict__ out,
      u64* __restrict__ hg, unsigned* __restrict__ flags)
{
  const int blk  = blockIdx.x;
  const int g    = blk >> 2;      // batch group (32)
  const int sl   = blk & 3;       // hidden slice (4)
  const int tid  = threadIdx.x;
  const int w    = tid >> 6;      // wave 0..7
  const int lane = tid & 63;
  const int q    = lane >> 4;
  const int l15  = lane & 15;     // batch within group
  const int gbase = g * BT;

  extern __shared__ char smem_raw[];
  short* h0s = (short*)smem_raw;          // [BT][KP] staged h0[s-1], kpos order
  short* h1s = h0s + BT * KP;             // [BT][KP] staged h1[s-2]
  float* xls = (float*)(h1s + BT * KP);   // [BT][XS] x preload
  float* wls = xls + BT * XS;             // [Pz][256] w_lin permuted to kpos order

  // ---- one-time: weights -> register A-fragments (permuted k gather) ----
  // B-frag elem j at kpos = kt*32 + q*8 + j; decode x = kt*4+q (slot),
  // k_true = (x>>3)*64 + (x&7)*4 + (j>>1) + 32*(j&1)
  s8v Wf[3][2][8];   // [mat: hh0, ih1, hh1][mti][kt]
  {
    const float* wsrc[3] = {w_hh0, w_ih1, w_hh1};
    #pragma unroll
    for (int mat = 0; mat < 3; ++mat) {
      #pragma unroll
      for (int mti = 0; mti < 2; ++mti) {
        int rr = (w + mti * 8) * 16 + l15;          // A-row: rr = unit*4+gate
        int grow = (rr & 3) * Hz + sl * 64 + (rr >> 2);
        const float* p = wsrc[mat] + (size_t)grow * Hz;
        #pragma unroll
        for (int kt = 0; kt < 8; ++kt) {
          s8v f;
          #pragma unroll
          for (int j = 0; j < 8; ++j) {
            int xk = kt * 4 + q;
            int ktrue = (xk >> 3) * 64 + (xk & 7) * 4 + (j >> 1) + 32 * (j & 1);
            f[j] = f2bf(p[ktrue]);
          }
          Wf[mat][mti][kt] = f;
        }
      }
    }
  }
  // per-lane epilogue constants: units uA = sl*64 + w*4+q, uB = uA+32
  const int uA = sl * 64 + w * 4 + q, uB = uA + 32;
  float wihA[4], wihB[4], b0A[4], b0B[4], b1A[4], b1B[4];
  #pragma unroll
  for (int r = 0; r < 4; ++r) {
    int ga_ = r * Hz + uA;
    int gb_ = r * Hz + uB;
    wihA[r] = w_ih0[ga_];              wihB[r] = w_ih0[gb_];
    b0A[r]  = b_ih0[ga_] + b_hh0[ga_]; b0B[r]  = b_ih0[gb_] + b_hh0[gb_];
    b1A[r]  = b_ih1[ga_] + b_hh1[ga_]; b1B[r]  = b_ih1[gb_] + b_hh1[gb_];
  }
  float c0A = 0.f, c0B = 0.f, c1A = 0.f, c1B = 0.f;   // cell states in VGPRs

  // ---- preload x (this group's 16 batches) and permuted w_lin (head) ----
  for (int i = tid; i < BT * (Tz / 4); i += THR) {
    int b = i >> 6, c4 = i & 63;
    f4v v = *(const f4v*)(x + (size_t)(gbase + b) * Tz + c4 * 4);
    *(f4v*)(xls + b * XS + c4 * 4) = v;
  }
  if (sl == 0) {
    for (int i = tid; i < Pz * Hz; i += THR) {
      int p = i >> 8, kpos = i & 255;
      int slw2 = kpos >> 3, inner = kpos & 7;
      int q2 = inner >> 1, j2 = inner & 1;
      int ktrue = (slw2 >> 3) * 64 + (slw2 & 7) * 4 + q2 + 32 * j2;
      wls[i] = w_lin[p * Hz + ktrue];
    }
  }

  const unsigned* myflags = flags + g * 32 + (lane & 3);  // group's 4 flags
  unsigned* myflag = flags + g * 32 + sl;

  for (int s = 0; s <= Tz; ++s) {
    // ---- A: wave0 polls: all 4 producers completed step s-1; barrier gates rest ----
    if (w == 0) {
      const unsigned expd = (unsigned)s;
      unsigned f = llc_load32(myflags);
      while (__ballot(f >= expd) != ~0ull) {
        __builtin_amdgcn_s_sleep(1);
        f = llc_load32(myflags);
      }
    }
    __syncthreads();   // barrier A: poll verdict gates all waves' stage loads

    // ---- B: stage combined words from parity (s+1)&1 = (s-1)&1 ----
    // word (slw, b, q) = lo32: h0 pair (uA,uB) | hi32: h1 pair, iter s-1
    {
      const u64* sp = hg + (size_t)((s + 1) & 1) * 65536;
      u64 r[4];
      #pragma unroll
      for (int k = 0; k < 2; ++k) {
        int i = tid + k * THR;
        int c = i & 1, b = (i >> 1) & 15, slw = i >> 5;
        size_t gi = ((size_t)slw * Bz + gbase + b) * 4 + 2 * c;
        r[2 * k]     = llc_load64(sp + gi);
        r[2 * k + 1] = llc_load64(sp + gi + 1);
      }
      #pragma unroll
      for (int k = 0; k < 2; ++k) {
        int i = tid + k * THR;
        int c = i & 1, b = (i >> 1) & 15, slw = i >> 5;
        u64 lo = r[2 * k], hi = r[2 * k + 1];
        *(u64*)(h0s + b * KP + slw * 8 + c * 4) =
            (u64)(unsigned)lo | ((u64)(unsigned)hi << 32);
        *(u64*)(h1s + b * KP + slw * 8 + c * 4) =
            (lo >> 32) | ((hi >> 32) << 32);
      }
    }
    __syncthreads();   // sync1: staged LDS visible

    // ---- C: fused MFMA (L0: 16, L1: 32); weights from regs; 16 b128 reads ----
    f4v a0A = {0.f,0.f,0.f,0.f}, a0B = {0.f,0.f,0.f,0.f};
    f4v a1A = {0.f,0.f,0.f,0.f}, a1B = {0.f,0.f,0.f,0.f};
    const short* H0f = h0s + l15 * KP + q * 8;
    const short* H1f = h1s + l15 * KP + q * 8;
    #pragma unroll
    for (int kt = 0; kt < 8; ++kt) {
      s8v h0v = *(const s8v*)(H0f + kt * 32);
      s8v h1v = *(const s8v*)(H1f + kt * 32);
      a0A = __builtin_amdgcn_mfma_f32_16x16x32_bf16(Wf[0][0][kt], h0v, a0A, 0, 0, 0);
      a0B = __builtin_amdgcn_mfma_f32_16x16x32_bf16(Wf[0][1][kt], h0v, a0B, 0, 0, 0);
      a1A = __builtin_amdgcn_mfma_f32_16x16x32_bf16(Wf[1][0][kt], h0v, a1A, 0, 0, 0);
      a1B = __builtin_amdgcn_mfma_f32_16x16x32_bf16(Wf[1][1][kt], h0v, a1B, 0, 0, 0);
      a1A = __builtin_amdgcn_mfma_f32_16x16x32_bf16(Wf[2][0][kt], h1v, a1A, 0, 0, 0);
      a1B = __builtin_amdgcn_mfma_f32_16x16x32_bf16(Wf[2][1][kt], h1v, a1B, 0, 0, 0);
    }

    // ---- D: in-register epilogues -> one packed u32 per layer ----
    unsigned pk0 = 0, pk1 = 0;
    if (s < Tz) {
      float xv = xls[l15 * XS + s];
      float iA = sigm  (a0A[0] + xv * wihA[0] + b0A[0]);
      float fA = sigm  (a0A[1] + xv * wihA[1] + b0A[1]);
      float gA = tanh_f(a0A[2] + xv * wihA[2] + b0A[2]);
      float oA = sigm  (a0A[3] + xv * wihA[3] + b0A[3]);
      c0A = fA * c0A + iA * gA;
      float iB = sigm  (a0B[0] + xv * wihB[0] + b0B[0]);
      float fB = sigm  (a0B[1] + xv * wihB[1] + b0B[1]);
      float gB = tanh_f(a0B[2] + xv * wihB[2] + b0B[2]);
      float oB = sigm  (a0B[3] + xv * wihB[3] + b0B[3]);
      c0B = fB * c0B + iB * gB;
      pk0 = (unsigned)(unsigned short)f2bf(oA * tanh_f(c0A))
          | ((unsigned)(unsigned short)f2bf(oB * tanh_f(c0B)) << 16);
    }
    if (s >= 1) {
      float iA = sigm  (a1A[0] + b1A[0]);
      float fA = sigm  (a1A[1] + b1A[1]);
      float gA = tanh_f(a1A[2] + b1A[2]);
      float oA = sigm  (a1A[3] + b1A[3]);
      c1A = fA * c1A + iA * gA;
      float iB = sigm  (a1B[0] + b1B[0]);
      float fB = sigm  (a1B[1] + b1B[1]);
      float gB = tanh_f(a1B[2] + b1B[2]);
      float oB = sigm  (a1B[3] + b1B[3]);
      c1B = fB * c1B + iB * gB;
      pk1 = (unsigned)(unsigned short)f2bf(oA * tanh_f(c1A))
          | ((unsigned)(unsigned short)f2bf(oB * tanh_f(c1B)) << 16);
    }

    // ---- E: ONE combined coalesced store (unconditional) ----
    // pk1=0 at s=0 is the true h1[-1]=0; pk0=0 at s=Tz is never read.
    {
      size_t base = (size_t)(sl * 8 + w) * 2048 + (size_t)(gbase + l15) * 4 + q;
      llc_store64(hg + (size_t)(s & 1) * 65536 + base,
                  (u64)pk0 | ((u64)pk1 << 32));
    }

    // ---- F: drain (per-wave vmcnt(0) inside __syncthreads) + publish ----
    __syncthreads();
    if (tid == 0)
      llc_store32(myflag, (unsigned)(s + 1));
  }

  // ---- final head (sl==0 blocks): out = h1[Tz-1] @ w_lin^T + b_lin ----
  // h1[Tz-1] = hi32 halves of combined words written at iter Tz, parity 0.
  if (sl == 0) {
    {
      const unsigned expd = (unsigned)(Tz + 1);
      unsigned f = llc_load32(myflags);
      while (__ballot(f >= expd) != ~0ull) {
        __builtin_amdgcn_s_sleep(1);
        f = llc_load32(myflags);
      }
    }
    const u64* sp = hg + (size_t)(Tz & 1) * 65536;   // parity 0
    for (int k = 0; k < 2; ++k) {
      int i = tid + k * THR;
      int c = i & 1, b = (i >> 1) & 15, slw = i >> 5;
      size_t gi = ((size_t)slw * Bz + gbase + b) * 4 + 2 * c;
      u64 lo = llc_load64(sp + gi);
      u64 hi = llc_load64(sp + gi + 1);
      *(u64*)(h0s + b * KP + slw * 8 + c * 4) = (lo >> 32) | ((hi >> 32) << 32);
    }
    __syncthreads();
    for (int i = tid; i < BT * Pz; i += THR) {
      int b = i / Pz, p = i - b * Pz;
      const float* wr = wls + p * Hz;
      float acc = b_lin[p];
      for (int kk = 0; kk < Hz; ++kk)
        acc += bf2f(h0s[b * KP + kk]) * wr[kk];   // both in kpos order
      out[(gbase + b) * Pz + p] = acc;
    }
  }
}

extern "C" void kernel_launch(void* const* d_in, const int* in_sizes, int n_in,
                              void* d_out, int out_size, void* d_ws, size_t ws_size,
                              hipStream_t stream) {
  const float* x     = (const float*)d_in[0];
  const float* w_ih0 = (const float*)d_in[1];
  const float* w_hh0 = (const float*)d_in[2];
  const float* b_ih0 = (const float*)d_in[3];
  const float* b_hh0 = (const float*)d_in[4];
  const float* w_ih1 = (const float*)d_in[5];
  const float* w_hh1 = (const float*)d_in[6];
  const float* b_ih1 = (const float*)d_in[7];
  const float* b_hh1 = (const float*)d_in[8];
  const float* w_lin = (const float*)d_in[9];
  const float* b_lin = (const float*)d_in[10];
  float* out = (float*)d_out;

  unsigned char* ws = (unsigned char*)d_ws;
  u64* hg         = (u64*)ws;                          // [2][65536] u64 (512 KB/parity)
  unsigned* flags = (unsigned*)(ws + (1 << 20));       // [32 groups][32] u32 (4 used)
  // memset(0): h data zeros (bf16 0x0000 = initial hidden state) + flags = 0
  hipMemsetAsync(d_ws, 0, (1 << 20) + 4096, stream);

  size_t lds_bytes = (size_t)(2 * BT) * KP * 2     // h staging
                   + (size_t)(BT * XS) * 4         // x preload
                   + (size_t)(Pz * Hz) * 4;        // permuted w_lin (head)
  hipFuncSetAttribute((const void*)lstm2,
                      hipFuncAttributeMaxDynamicSharedMemorySize, (int)lds_bytes);
  lstm2<<<GB * GS, THR, lds_bytes, stream>>>(x, w_ih0, w_hh0, b_ih0, b_hh0,
                                             w_ih1, w_hh1, b_ih1, b_hh1,
                                             w_lin, b_lin, out, hg, flags);
}

// Round 8
// 1019.925 us; speedup vs baseline: 1.0769x; 1.0658x over previous
//
#include <hip/hip_runtime.h>

// Problem constants
constexpr int Bz = 512;   // batch
constexpr int Tz = 256;   // seq len
constexpr int Hz = 256;   // hidden
constexpr int Pz = 14;    // predict dim
constexpr int GB = 32;    // batch groups
constexpr int GS = 8;     // hidden slices per group (R14-proven shape)
constexpr int BT = 16;    // batch per group (512/32)
constexpr int KP = 264;   // LDS h row stride (shorts)
constexpr int XS = 260;   // x LDS row stride (floats)
constexpr int HBsz = BT * KP;   // shorts per h stage buffer

typedef short s8v __attribute__((ext_vector_type(8)));
typedef float f4v __attribute__((ext_vector_type(4)));
typedef unsigned long long u64;

__device__ __forceinline__ short f2bf(float f) {
  unsigned u = __float_as_uint(f);
  u = (u + 0x7fffu + ((u >> 16) & 1u)) >> 16;   // RNE
  return (short)u;
}
__device__ __forceinline__ float bf2f(short s) {
  return __uint_as_float(((unsigned)(unsigned short)s) << 16);
}
// Fast gates (R11/R14-proven numerics, same absmax as libm path)
__device__ __forceinline__ float sigm(float v) {
  return __builtin_amdgcn_rcpf(1.0f + __builtin_amdgcn_exp2f(-1.442695041f * v));
}
__device__ __forceinline__ float tanh_f(float v) {
  return 1.0f - 2.0f * __builtin_amdgcn_rcpf(__builtin_amdgcn_exp2f(2.885390082f * v) + 1.0f);
}

__device__ __forceinline__ u64 llc_load64(const u64* p) {
  return __hip_atomic_load(p, __ATOMIC_RELAXED, __HIP_MEMORY_SCOPE_AGENT);
}
__device__ __forceinline__ unsigned llc_load32(const unsigned* p) {
  return __hip_atomic_load(p, __ATOMIC_RELAXED, __HIP_MEMORY_SCOPE_AGENT);
}
__device__ __forceinline__ void llc_store64(u64* p, u64 v) {
  __hip_atomic_store(p, v, __ATOMIC_RELAXED, __HIP_MEMORY_SCOPE_AGENT);
}

// R17 = R14 (727us proven: 8 blocks x 256 thr/group, combined u64 h-word,
// wave0 poll + barrier A, fast gates) with the publish chain shortened:
//  1. Per-wave atomic publish: each wave, after its OWN s_waitcnt vmcnt(0),
//     does atomicAdd(ctr[g][sl], 1) from lane0. ctr >= 4s <=> block done
//     with step s-1. Atomics execute at the TCC (memory-side) -> no line
//     ping-pong; consumers keep R14's wave0-only poll of one 32B line.
//     NOT R13's failure mode (32 plain stores from 32 CUs + all-wave poll).
//  2. F-barrier deleted; LDS stage buffers double-buffered by step parity.
//     WAR intra-block: stage(s+2) reuses buf[s&1]; barriers A(s+1),
//     sync1(s+1), A(s+2) all intervene => every wave finished MFMA(s).
// Ordering basis (unchanged from R5/R9/R14): wave's data stores are TCC-acked
// by its vmcnt(0) BEFORE the atomic issues => data at LLC before flag (RAW);
// ctr >= 4s => every peer wave's step-s-1 stage loads returned (vmcnt(0)
// covers loads) => parity overwrite at step s safe (WAR). Barriers: 2/step.
__global__ void __launch_bounds__(256, 1)
lstm2(const float* __restrict__ x,
      const float* __restrict__ w_ih0, const float* __restrict__ w_hh0,
      const float* __restrict__ b_ih0, const float* __restrict__ b_hh0,
      const float* __restrict__ w_ih1, const float* __restrict__ w_hh1,
      const float* __restrict__ b_ih1, const float* __restrict__ b_hh1,
      const float* __restrict__ w_lin, const float* __restrict__ b_lin,
      float* __restrict__ out,
      u64* __restrict__ hg, unsigned* __restrict__ flags)
{
  const int blk  = blockIdx.x;
  const int g    = blk >> 3;      // batch group (32)
  const int sl   = blk & 7;       // hidden slice (8)
  const int tid  = threadIdx.x;
  const int w    = tid >> 6;      // wave
  const int lane = tid & 63;
  const int q    = lane >> 4;
  const int l15  = lane & 15;     // batch within group
  const int gbase = g * BT;

  extern __shared__ char smem_raw[];
  short* hstage = (short*)smem_raw;             // [2 parities][h0|h1][BT][KP]
  float* xls = (float*)(hstage + 4 * HBsz);     // [BT][XS] x preload
  float* wls = xls + BT * XS;                   // [Pz][256] w_lin kpos order

  // ---- one-time: weights -> register A-fragments (permuted k gather) ----
  // kpos = sl*32 + w*8 + q*2 + j  <->  k_true = sl*32 + w*4 + q + 16*j
  s8v Wf[3][2][8];   // [mat: hh0, ih1, hh1][mti][kt]
  {
    const float* wsrc[3] = {w_hh0, w_ih1, w_hh1};
    #pragma unroll
    for (int mat = 0; mat < 3; ++mat) {
      #pragma unroll
      for (int mti = 0; mti < 2; ++mti) {
        int rr = (w + mti * 4) * 16 + l15;          // rr = unit*4+gate
        int grow = (rr & 3) * Hz + sl * 32 + (rr >> 2);
        const float* p = wsrc[mat] + (size_t)grow * Hz;
        #pragma unroll
        for (int kt = 0; kt < 8; ++kt) {
          s8v f;
          #pragma unroll
          for (int j = 0; j < 8; ++j) {
            int ktrue = kt * 32 + q * 4 + (j >> 1) + 16 * (j & 1);
            f[j] = f2bf(p[ktrue]);
          }
          Wf[mat][mti][kt] = f;
        }
      }
    }
  }
  // per-lane epilogue constants: units uA = w*4+q, uB = 16+uA; gates r=0..3
  const int uA = w * 4 + q, uB = 16 + w * 4 + q;
  float wihA[4], wihB[4], b0A[4], b0B[4], b1A[4], b1B[4];
  #pragma unroll
  for (int r = 0; r < 4; ++r) {
    int ga_ = r * Hz + sl * 32 + uA;
    int gb_ = r * Hz + sl * 32 + uB;
    wihA[r] = w_ih0[ga_];              wihB[r] = w_ih0[gb_];
    b0A[r]  = b_ih0[ga_] + b_hh0[ga_]; b0B[r]  = b_ih0[gb_] + b_hh0[gb_];
    b1A[r]  = b_ih1[ga_] + b_hh1[ga_]; b1B[r]  = b_ih1[gb_] + b_hh1[gb_];
  }
  float c0A = 0.f, c0B = 0.f, c1A = 0.f, c1B = 0.f;   // cell states in VGPRs

  // ---- preload x (this group's 16 batches) and permuted w_lin (head) ----
  for (int i = tid; i < BT * (Tz / 4); i += 256) {
    int b = i >> 6, c4 = i & 63;
    f4v v = *(const f4v*)(x + (size_t)(gbase + b) * Tz + c4 * 4);
    *(f4v*)(xls + b * XS + c4 * 4) = v;
  }
  if (sl == 0) {
    for (int i = tid; i < Pz * Hz; i += 256) {
      int p = i >> 8, kpos = i & 255;
      int sl2 = kpos >> 5, w2 = (kpos >> 3) & 3, q2 = (kpos >> 1) & 3, jj = kpos & 1;
      wls[i] = w_lin[p * Hz + sl2 * 32 + w2 * 4 + q2 + 16 * jj];
    }
  }

  // group's 8 counters live in one 64B-aligned span (16 u32 stride/group)
  const unsigned* myctrs = flags + g * 16 + (lane & 7);
  unsigned* myctr = flags + g * 16 + sl;

  // per-thread stage decode (same for every step)
  int cc[4], bb[4], ss[4];
  #pragma unroll
  for (int k = 0; k < 4; ++k) {
    int i = tid + k * 256;
    cc[k] = i & 1; bb[k] = (i >> 1) & 15; ss[k] = i >> 5;
  }

  for (int s = 0; s <= Tz; ++s) {
    // ---- A: wave0 polls: all 8 producers' ctr >= 4s; barrier gates rest ----
    if (w == 0) {
      const unsigned expd = 4u * (unsigned)s;
      unsigned f = llc_load32(myctrs);
      while (__ballot(f >= expd) != ~0ull) {
        __builtin_amdgcn_s_sleep(1);
        f = llc_load32(myctrs);
      }
    }
    __syncthreads();   // barrier A: poll verdict gates all waves' stage loads

    // ---- B: stage combined words into LDS buf[s&1] ----
    short* hb0 = hstage + (s & 1) * (2 * HBsz);
    short* hb1 = hb0 + HBsz;
    {
      const u64* sp = hg + (size_t)((s + 1) & 1) * 65536;
      u64 r[8];
      #pragma unroll
      for (int k = 0; k < 4; ++k) {
        size_t gi = ((size_t)ss[k] * Bz + gbase + bb[k]) * 4 + 2 * cc[k];
        r[2 * k]     = llc_load64(sp + gi);
        r[2 * k + 1] = llc_load64(sp + gi + 1);
      }
      #pragma unroll
      for (int k = 0; k < 4; ++k) {
        u64 lo = r[2 * k], hi = r[2 * k + 1];
        *(u64*)(hb0 + bb[k] * KP + ss[k] * 8 + cc[k] * 4) =
            (u64)(unsigned)lo | ((u64)(unsigned)hi << 32);
        *(u64*)(hb1 + bb[k] * KP + ss[k] * 8 + cc[k] * 4) =
            (lo >> 32) | ((hi >> 32) << 32);
      }
    }
    __syncthreads();   // sync1: staged LDS visible

    // ---- C: fused MFMA (L0: 16, L1: 32); weights from regs; 16 b128 reads ----
    f4v a0A = {0.f,0.f,0.f,0.f}, a0B = {0.f,0.f,0.f,0.f};
    f4v a1A = {0.f,0.f,0.f,0.f}, a1B = {0.f,0.f,0.f,0.f};
    const short* H0f = hb0 + l15 * KP + q * 8;
    const short* H1f = hb1 + l15 * KP + q * 8;
    #pragma unroll
    for (int kt = 0; kt < 8; ++kt) {
      s8v h0v = *(const s8v*)(H0f + kt * 32);
      s8v h1v = *(const s8v*)(H1f + kt * 32);
      a0A = __builtin_amdgcn_mfma_f32_16x16x32_bf16(Wf[0][0][kt], h0v, a0A, 0, 0, 0);
      a0B = __builtin_amdgcn_mfma_f32_16x16x32_bf16(Wf[0][1][kt], h0v, a0B, 0, 0, 0);
      a1A = __builtin_amdgcn_mfma_f32_16x16x32_bf16(Wf[1][0][kt], h0v, a1A, 0, 0, 0);
      a1B = __builtin_amdgcn_mfma_f32_16x16x32_bf16(Wf[1][1][kt], h0v, a1B, 0, 0, 0);
      a1A = __builtin_amdgcn_mfma_f32_16x16x32_bf16(Wf[2][0][kt], h1v, a1A, 0, 0, 0);
      a1B = __builtin_amdgcn_mfma_f32_16x16x32_bf16(Wf[2][1][kt], h1v, a1B, 0, 0, 0);
    }

    // ---- D: in-register epilogues -> one packed u32 per layer ----
    unsigned pk0 = 0, pk1 = 0;
    if (s < Tz) {
      float xv = xls[l15 * XS + s];
      float iA = sigm  (a0A[0] + xv * wihA[0] + b0A[0]);
      float fA = sigm  (a0A[1] + xv * wihA[1] + b0A[1]);
      float gA = tanh_f(a0A[2] + xv * wihA[2] + b0A[2]);
      float oA = sigm  (a0A[3] + xv * wihA[3] + b0A[3]);
      c0A = fA * c0A + iA * gA;
      float iB = sigm  (a0B[0] + xv * wihB[0] + b0B[0]);
      float fB = sigm  (a0B[1] + xv * wihB[1] + b0B[1]);
      float gB = tanh_f(a0B[2] + xv * wihB[2] + b0B[2]);
      float oB = sigm  (a0B[3] + xv * wihB[3] + b0B[3]);
      c0B = fB * c0B + iB * gB;
      pk0 = (unsigned)(unsigned short)f2bf(oA * tanh_f(c0A))
          | ((unsigned)(unsigned short)f2bf(oB * tanh_f(c0B)) << 16);
    }
    if (s >= 1) {
      float iA = sigm  (a1A[0] + b1A[0]);
      float fA = sigm  (a1A[1] + b1A[1]);
      float gA = tanh_f(a1A[2] + b1A[2]);
      float oA = sigm  (a1A[3] + b1A[3]);
      c1A = fA * c1A + iA * gA;
      float iB = sigm  (a1B[0] + b1B[0]);
      float fB = sigm  (a1B[1] + b1B[1]);
      float gB = tanh_f(a1B[2] + b1B[2]);
      float oB = sigm  (a1B[3] + b1B[3]);
      c1B = fB * c1B + iB * gB;
      pk1 = (unsigned)(unsigned short)f2bf(oA * tanh_f(c1A))
          | ((unsigned)(unsigned short)f2bf(oB * tanh_f(c1B)) << 16);
    }

    // ---- E: ONE combined coalesced store (unconditional) ----
    // pk1=0 at s=0 is the true h1[-1]=0; pk0=0 at s=Tz is never read.
    {
      size_t base = (size_t)(sl * 4 + w) * 2048 + (size_t)(gbase + l15) * 4 + q;
      llc_store64(hg + (size_t)(s & 1) * 65536 + base,
                  (u64)pk0 | ((u64)pk1 << 32));
    }

    // ---- F: per-wave drain -> per-wave atomic publish (no barrier) ----
    asm volatile("s_waitcnt vmcnt(0)" ::: "memory");
    __builtin_amdgcn_sched_barrier(0);
    if (lane == 0)
      __hip_atomic_fetch_add(myctr, 1u, __ATOMIC_RELAXED,
                             __HIP_MEMORY_SCOPE_AGENT);
  }

  // ---- final head (sl==0 blocks): out = h1[Tz-1] @ w_lin^T + b_lin ----
  // h1[Tz-1] = hi32 halves of combined words written at iter Tz, parity 0.
  if (sl == 0) {
    {
      const unsigned expd = 4u * (unsigned)(Tz + 1);
      unsigned f = llc_load32(myctrs);
      while (__ballot(f >= expd) != ~0ull) {
        __builtin_amdgcn_s_sleep(1);
        f = llc_load32(myctrs);
      }
    }
    // stage into parity-1 h0 region (last touched at MFMA(Tz-1); all waves
    // passed A-sync(Tz) since, and buffer parity-0 readers don't alias it)
    short* hb = hstage + 1 * (2 * HBsz);
    const u64* sp = hg + (size_t)(Tz & 1) * 65536;   // parity 0
    for (int k = 0; k < 4; ++k) {
      size_t gi = ((size_t)ss[k] * Bz + gbase + bb[k]) * 4 + 2 * cc[k];
      u64 lo = llc_load64(sp + gi);
      u64 hi = llc_load64(sp + gi + 1);
      *(u64*)(hb + bb[k] * KP + ss[k] * 8 + cc[k] * 4) =
          (lo >> 32) | ((hi >> 32) << 32);
    }
    __syncthreads();
    for (int i = tid; i < BT * Pz; i += 256) {
      int b = i / Pz, p = i - b * Pz;
      const float* wr = wls + p * Hz;
      float acc = b_lin[p];
      for (int kk = 0; kk < Hz; ++kk)
        acc += bf2f(hb[b * KP + kk]) * wr[kk];   // both in kpos order
      out[(gbase + b) * Pz + p] = acc;
    }
  }
}

extern "C" void kernel_launch(void* const* d_in, const int* in_sizes, int n_in,
                              void* d_out, int out_size, void* d_ws, size_t ws_size,
                              hipStream_t stream) {
  const float* x     = (const float*)d_in[0];
  const float* w_ih0 = (const float*)d_in[1];
  const float* w_hh0 = (const float*)d_in[2];
  const float* b_ih0 = (const float*)d_in[3];
  const float* b_hh0 = (const float*)d_in[4];
  const float* w_ih1 = (const float*)d_in[5];
  const float* w_hh1 = (const float*)d_in[6];
  const float* b_ih1 = (const float*)d_in[7];
  const float* b_hh1 = (const float*)d_in[8];
  const float* w_lin = (const float*)d_in[9];
  const float* b_lin = (const float*)d_in[10];
  float* out = (float*)d_out;

  unsigned char* ws = (unsigned char*)d_ws;
  u64* hg         = (u64*)ws;                          // [2][65536] u64 (512 KB/parity)
  unsigned* flags = (unsigned*)(ws + (1 << 20));       // [32 groups][16] u32 ctrs
  // memset(0): h data zeros (bf16 0x0000 = initial hidden state) + ctrs = 0
  hipMemsetAsync(d_ws, 0, (1 << 20) + 4096, stream);

  size_t lds_bytes = (size_t)(4 * HBsz) * 2        // h staging, double-buffered
                   + (size_t)(BT * XS) * 4         // x preload
                   + (size_t)(Pz * Hz) * 4;        // permuted w_lin (head)
  hipFuncSetAttribute((const void*)lstm2,
                      hipFuncAttributeMaxDynamicSharedMemorySize, (int)lds_bytes);
  lstm2<<<GB * GS, 256, lds_bytes, stream>>>(x, w_ih0, w_hh0, b_ih0, b_hh0,
                                             w_ih1, w_hh1, b_ih1, b_hh1,
                                             w_lin, b_lin, out, hg, flags);
}

// Round 9
// 859.634 us; speedup vs baseline: 1.2777x; 1.1865x over previous
//
#include <hip/hip_runtime.h>

// Problem constants
constexpr int Bz = 512;   // batch
constexpr int Tz = 256;   // seq len
constexpr int Hz = 256;   // hidden
constexpr int Pz = 14;    // predict dim
constexpr int GB = 32;    // batch groups
constexpr int GS = 8;     // hidden slices per group
constexpr int BT = 16;    // batch per group (512/32)
constexpr int KP = 264;   // LDS h row stride (shorts)
constexpr int XS = 260;   // x LDS row stride (floats)

typedef short s8v __attribute__((ext_vector_type(8)));
typedef float f4v __attribute__((ext_vector_type(4)));
typedef unsigned long long u64;

__device__ __forceinline__ short f2bf(float f) {
  unsigned u = __float_as_uint(f);
  u = (u + 0x7fffu + ((u >> 16) & 1u)) >> 16;   // RNE
  return (short)u;
}
__device__ __forceinline__ float bf2f(short s) {
  return __uint_as_float(((unsigned)(unsigned short)s) << 16);
}
// Fast gates (R11/R14-proven numerics)
__device__ __forceinline__ float sigm(float v) {
  return __builtin_amdgcn_rcpf(1.0f + __builtin_amdgcn_exp2f(-1.442695041f * v));
}
__device__ __forceinline__ float tanh_f(float v) {
  return 1.0f - 2.0f * __builtin_amdgcn_rcpf(__builtin_amdgcn_exp2f(2.885390082f * v) + 1.0f);
}

__device__ __forceinline__ u64 llc_load64(const u64* p) {
  return __hip_atomic_load(p, __ATOMIC_RELAXED, __HIP_MEMORY_SCOPE_AGENT);
}
__device__ __forceinline__ unsigned llc_load32(const unsigned* p) {
  return __hip_atomic_load(p, __ATOMIC_RELAXED, __HIP_MEMORY_SCOPE_AGENT);
}
__device__ __forceinline__ void llc_store32(unsigned* p, unsigned v) {
  __hip_atomic_store(p, v, __ATOMIC_RELAXED, __HIP_MEMORY_SCOPE_AGENT);
}

// R18: LAYER-SPLIT PIPELINE. 512 blocks = 256 L0-blocks + 256 L1-blocks
// (role = blk>>8). Each role keeps R14's proven per-step skeleton verbatim:
//   poll(wave0) -> barrier A -> stage -> sync1 -> MFMA -> epilogue ->
//   store -> F-barrier (per-wave vmcnt(0) drain inside) -> tid0 flag.
// R13/R17 lesson: exactly ONE consolidated publish per block per step.
//
// Chains: L0 recurrence h0[s]=LSTM0(h0[s-1],x[s]) carries only 16 MFMA/wave,
// 4 stage loads, half epilogue. L1: h1[t]=LSTM1(h1[t-1],h0[t]) runs on
// separate blocks, consuming h0 through a 4-DEEP RING (slot = s&3) so L0
// can lead by up to 3 steps.
//
// Flags (per group, one 64B line): [0..7] L0 slice flags, [8..15] L1.
// Gates:
//   L0 step s: L0flags >= s (RAW h0[s-1]; WAR on peers' stage loads)
//              AND L1flags >= s-3 (WAR: slot s&3 holds h0[s-4]; L1 read it
//              at its step s-4, completed per flag >= s-3). s<3 -> 0 (pass).
//   L1 step t: L0flags >= t+1 (RAW h0[t]) AND L1flags >= t (RAW h1[t-1],
//              parity (t-1)&1; WAR on h1 parity overwrite).
// Deadlock-free: if L1 is >3 behind L0, its gate L0>=t+1 is satisfied ->
// L1 advances; L0 only waits when >=4 ahead. memset(0): h ring/parities
// zero (h[-1]=0) and flags zero.
// Co-residency (required: L1 spins on L0 flags): 512 blocks, 2/CU exactly.
// launch_bounds(256,2) caps VGPR at 256 (both roles ~190-210) -> 8 waves/CU.
__global__ void __launch_bounds__(256, 2)
lstm2(const float* __restrict__ x,
      const float* __restrict__ w_ih0, const float* __restrict__ w_hh0,
      const float* __restrict__ b_ih0, const float* __restrict__ b_hh0,
      const float* __restrict__ w_ih1, const float* __restrict__ w_hh1,
      const float* __restrict__ b_ih1, const float* __restrict__ b_hh1,
      const float* __restrict__ w_lin, const float* __restrict__ b_lin,
      float* __restrict__ out,
      unsigned* __restrict__ h0g, unsigned* __restrict__ h1g,
      unsigned* __restrict__ flags)
{
  const int blk  = blockIdx.x;
  const int role = blk >> 8;      // 0 = layer0, 1 = layer1
  const int sub  = blk & 255;
  const int g    = sub >> 3;      // batch group (32)
  const int sl   = sub & 7;       // hidden slice (8)
  const int tid  = threadIdx.x;
  const int w    = tid >> 6;      // wave
  const int lane = tid & 63;
  const int q    = lane >> 4;
  const int l15  = lane & 15;     // batch within group
  const int gbase = g * BT;

  extern __shared__ char smem_raw[];
  short* h0s = (short*)smem_raw;          // [BT][KP] staged h0, kpos order
  short* h1s = h0s + BT * KP;             // [BT][KP] staged h1 (role1)
  float* xls = (float*)(h1s + BT * KP);   // [BT][XS] x preload (role0)
  float* wls = xls + BT * XS;             // [Pz][256] w_lin kpos order (role1 sl0)

  // per-thread stage decode (R9-proven): i -> (c, b, slw)
  int cc[4], bb[4], ss[4];
  #pragma unroll
  for (int k = 0; k < 4; ++k) {
    int i = tid + k * 256;
    cc[k] = i & 1; bb[k] = (i >> 1) & 15; ss[k] = i >> 5;
  }
  // data store base (u32 slab layout, R9-proven)
  const size_t stbase = (size_t)(sl * 4 + w) * 2048 + (size_t)(gbase + l15) * 4 + q;

  if (role == 0) {
    // ================= LAYER-0 BLOCK =================
    // weights: w_hh0 slice -> Wf0[2][8]; kpos gather (R14-proven decode)
    s8v Wf0[2][8];
    #pragma unroll
    for (int mti = 0; mti < 2; ++mti) {
      int rr = (w + mti * 4) * 16 + l15;
      int grow = (rr & 3) * Hz + sl * 32 + (rr >> 2);
      const float* p = w_hh0 + (size_t)grow * Hz;
      #pragma unroll
      for (int kt = 0; kt < 8; ++kt) {
        s8v f;
        #pragma unroll
        for (int j = 0; j < 8; ++j) {
          int ktrue = kt * 32 + q * 4 + (j >> 1) + 16 * (j & 1);
          f[j] = f2bf(p[ktrue]);
        }
        Wf0[mti][kt] = f;
      }
    }
    const int uA = w * 4 + q, uB = 16 + w * 4 + q;
    float wihA[4], wihB[4], b0A[4], b0B[4];
    #pragma unroll
    for (int r = 0; r < 4; ++r) {
      int ga_ = r * Hz + sl * 32 + uA;
      int gb_ = r * Hz + sl * 32 + uB;
      wihA[r] = w_ih0[ga_];              wihB[r] = w_ih0[gb_];
      b0A[r]  = b_ih0[ga_] + b_hh0[ga_]; b0B[r]  = b_ih0[gb_] + b_hh0[gb_];
    }
    float c0A = 0.f, c0B = 0.f;

    for (int i = tid; i < BT * (Tz / 4); i += 256) {
      int b = i >> 6, c4 = i & 63;
      f4v v = *(const f4v*)(x + (size_t)(gbase + b) * Tz + c4 * 4);
      *(f4v*)(xls + b * XS + c4 * 4) = v;
    }

    for (int s = 0; s < Tz; ++s) {
      // A: poll L0flags >= s (lanes 0-7) and L1flags >= s-3 (lanes 8-15)
      if (w == 0) {
        const unsigned lf = lane & 15;
        const unsigned e = (lf < 8) ? (unsigned)s
                                    : (unsigned)(s >= 3 ? s - 3 : 0);
        const unsigned* fp = flags + g * 32 + lf;
        unsigned f = llc_load32(fp);
        while (__ballot(f >= e) != ~0ull) {
          __builtin_amdgcn_s_sleep(1);
          f = llc_load32(fp);
        }
      }
      __syncthreads();   // barrier A

      // B: stage h0[s-1] from ring slot (s-1)&3
      {
        const u64* sp = (const u64*)h0g + (size_t)((s - 1) & 3) * 32768;
        u64 r[4];
        #pragma unroll
        for (int k = 0; k < 4; ++k)
          r[k] = llc_load64(sp + ((size_t)ss[k] * Bz + gbase + bb[k]) * 2 + cc[k]);
        #pragma unroll
        for (int k = 0; k < 4; ++k)
          *(u64*)(h0s + bb[k] * KP + ss[k] * 8 + cc[k] * 4) = r[k];
      }
      __syncthreads();   // sync1

      // C: 16 MFMA
      f4v a0A = {0.f,0.f,0.f,0.f}, a0B = {0.f,0.f,0.f,0.f};
      const short* H0f = h0s + l15 * KP + q * 8;
      #pragma unroll
      for (int kt = 0; kt < 8; ++kt) {
        s8v h0v = *(const s8v*)(H0f + kt * 32);
        a0A = __builtin_amdgcn_mfma_f32_16x16x32_bf16(Wf0[0][kt], h0v, a0A, 0, 0, 0);
        a0B = __builtin_amdgcn_mfma_f32_16x16x32_bf16(Wf0[1][kt], h0v, a0B, 0, 0, 0);
      }

      // D: epilogue -> packed u32
      float xv = xls[l15 * XS + s];
      float iA = sigm  (a0A[0] + xv * wihA[0] + b0A[0]);
      float fA = sigm  (a0A[1] + xv * wihA[1] + b0A[1]);
      float gA = tanh_f(a0A[2] + xv * wihA[2] + b0A[2]);
      float oA = sigm  (a0A[3] + xv * wihA[3] + b0A[3]);
      c0A = fA * c0A + iA * gA;
      float iB = sigm  (a0B[0] + xv * wihB[0] + b0B[0]);
      float fB = sigm  (a0B[1] + xv * wihB[1] + b0B[1]);
      float gB = tanh_f(a0B[2] + xv * wihB[2] + b0B[2]);
      float oB = sigm  (a0B[3] + xv * wihB[3] + b0B[3]);
      c0B = fB * c0B + iB * gB;
      unsigned pk0 = (unsigned)(unsigned short)f2bf(oA * tanh_f(c0A))
                   | ((unsigned)(unsigned short)f2bf(oB * tanh_f(c0B)) << 16);

      // E: store h0[s] into ring slot s&3
      llc_store32(h0g + (size_t)(s & 3) * 65536 + stbase, pk0);

      // F: drain (per-wave vmcnt(0) in __syncthreads) + publish
      __syncthreads();
      if (tid == 0)
        llc_store32(flags + g * 32 + sl, (unsigned)(s + 1));
    }
  } else {
    // ================= LAYER-1 BLOCK =================
    // weights: w_ih1 -> Wf[0], w_hh1 -> Wf[1]
    s8v Wf[2][2][8];
    {
      const float* wsrc[2] = {w_ih1, w_hh1};
      #pragma unroll
      for (int mat = 0; mat < 2; ++mat) {
        #pragma unroll
        for (int mti = 0; mti < 2; ++mti) {
          int rr = (w + mti * 4) * 16 + l15;
          int grow = (rr & 3) * Hz + sl * 32 + (rr >> 2);
          const float* p = wsrc[mat] + (size_t)grow * Hz;
          #pragma unroll
          for (int kt = 0; kt < 8; ++kt) {
            s8v f;
            #pragma unroll
            for (int j = 0; j < 8; ++j) {
              int ktrue = kt * 32 + q * 4 + (j >> 1) + 16 * (j & 1);
              f[j] = f2bf(p[ktrue]);
            }
            Wf[mat][mti][kt] = f;
          }
        }
      }
    }
    const int uA = w * 4 + q, uB = 16 + w * 4 + q;
    float b1A[4], b1B[4];
    #pragma unroll
    for (int r = 0; r < 4; ++r) {
      int ga_ = r * Hz + sl * 32 + uA;
      int gb_ = r * Hz + sl * 32 + uB;
      b1A[r] = b_ih1[ga_] + b_hh1[ga_];
      b1B[r] = b_ih1[gb_] + b_hh1[gb_];
    }
    float c1A = 0.f, c1B = 0.f;

    if (sl == 0) {
      for (int i = tid; i < Pz * Hz; i += 256) {
        int p = i >> 8, kpos = i & 255;
        int sl2 = kpos >> 5, w2 = (kpos >> 3) & 3, q2 = (kpos >> 1) & 3, jj = kpos & 1;
        wls[i] = w_lin[p * Hz + sl2 * 32 + w2 * 4 + q2 + 16 * jj];
      }
    }

    for (int t = 0; t < Tz; ++t) {
      // A: poll L0flags >= t+1 (lanes 0-7) and L1flags >= t (lanes 8-15)
      if (w == 0) {
        const unsigned lf = lane & 15;
        const unsigned e = (lf < 8) ? (unsigned)(t + 1) : (unsigned)t;
        const unsigned* fp = flags + g * 32 + lf;
        unsigned f = llc_load32(fp);
        while (__ballot(f >= e) != ~0ull) {
          __builtin_amdgcn_s_sleep(1);
          f = llc_load32(fp);
        }
      }
      __syncthreads();   // barrier A

      // B: stage h0[t] (ring slot t&3) and h1[t-1] (parity (t-1)&1)
      {
        const u64* sp0 = (const u64*)h0g + (size_t)(t & 3) * 32768;
        const u64* sp1 = (const u64*)h1g + (size_t)((t - 1) & 1) * 32768;
        u64 r0[4], r1[4];
        #pragma unroll
        for (int k = 0; k < 4; ++k) {
          size_t gi = ((size_t)ss[k] * Bz + gbase + bb[k]) * 2 + cc[k];
          r0[k] = llc_load64(sp0 + gi);
          r1[k] = llc_load64(sp1 + gi);
        }
        #pragma unroll
        for (int k = 0; k < 4; ++k) {
          *(u64*)(h0s + bb[k] * KP + ss[k] * 8 + cc[k] * 4) = r0[k];
          *(u64*)(h1s + bb[k] * KP + ss[k] * 8 + cc[k] * 4) = r1[k];
        }
      }
      __syncthreads();   // sync1

      // C: 32 MFMA (ih1 x h0[t] + hh1 x h1[t-1])
      f4v a1A = {0.f,0.f,0.f,0.f}, a1B = {0.f,0.f,0.f,0.f};
      const short* H0f = h0s + l15 * KP + q * 8;
      const short* H1f = h1s + l15 * KP + q * 8;
      #pragma unroll
      for (int kt = 0; kt < 8; ++kt) {
        s8v h0v = *(const s8v*)(H0f + kt * 32);
        s8v h1v = *(const s8v*)(H1f + kt * 32);
        a1A = __builtin_amdgcn_mfma_f32_16x16x32_bf16(Wf[0][0][kt], h0v, a1A, 0, 0, 0);
        a1B = __builtin_amdgcn_mfma_f32_16x16x32_bf16(Wf[0][1][kt], h0v, a1B, 0, 0, 0);
        a1A = __builtin_amdgcn_mfma_f32_16x16x32_bf16(Wf[1][0][kt], h1v, a1A, 0, 0, 0);
        a1B = __builtin_amdgcn_mfma_f32_16x16x32_bf16(Wf[1][1][kt], h1v, a1B, 0, 0, 0);
      }

      // D: epilogue -> packed u32
      float iA = sigm  (a1A[0] + b1A[0]);
      float fA = sigm  (a1A[1] + b1A[1]);
      float gA = tanh_f(a1A[2] + b1A[2]);
      float oA = sigm  (a1A[3] + b1A[3]);
      c1A = fA * c1A + iA * gA;
      float iB = sigm  (a1B[0] + b1B[0]);
      float fB = sigm  (a1B[1] + b1B[1]);
      float gB = tanh_f(a1B[2] + b1B[2]);
      float oB = sigm  (a1B[3] + b1B[3]);
      c1B = fB * c1B + iB * gB;
      unsigned pk1 = (unsigned)(unsigned short)f2bf(oA * tanh_f(c1A))
                   | ((unsigned)(unsigned short)f2bf(oB * tanh_f(c1B)) << 16);

      // E: store h1[t] at parity t&1
      llc_store32(h1g + (size_t)(t & 1) * 65536 + stbase, pk1);

      // F: drain + publish
      __syncthreads();
      if (tid == 0)
        llc_store32(flags + g * 32 + 8 + sl, (unsigned)(t + 1));
    }

    // head: sl==0 L1-block: out = h1[Tz-1] @ w_lin^T + b_lin (parity 1)
    if (sl == 0) {
      {
        const unsigned expd = (unsigned)Tz;
        const unsigned* fp = flags + g * 32 + 8 + (lane & 7);
        unsigned f = llc_load32(fp);
        while (__ballot(f >= expd) != ~0ull) {
          __builtin_amdgcn_s_sleep(1);
          f = llc_load32(fp);
        }
      }
      const u64* sp = (const u64*)h1g + (size_t)((Tz - 1) & 1) * 32768;
      for (int k = 0; k < 4; ++k) {
        u64 v = llc_load64(sp + ((size_t)ss[k] * Bz + gbase + bb[k]) * 2 + cc[k]);
        *(u64*)(h0s + bb[k] * KP + ss[k] * 8 + cc[k] * 4) = v;
      }
      __syncthreads();
      for (int i = tid; i < BT * Pz; i += 256) {
        int b = i / Pz, p = i - b * Pz;
        const float* wr = wls + p * Hz;
        float acc = b_lin[p];
        for (int kk = 0; kk < Hz; ++kk)
          acc += bf2f(h0s[b * KP + kk]) * wr[kk];   // both in kpos order
        out[(gbase + b) * Pz + p] = acc;
      }
    }
  }
}

extern "C" void kernel_launch(void* const* d_in, const int* in_sizes, int n_in,
                              void* d_out, int out_size, void* d_ws, size_t ws_size,
                              hipStream_t stream) {
  const float* x     = (const float*)d_in[0];
  const float* w_ih0 = (const float*)d_in[1];
  const float* w_hh0 = (const float*)d_in[2];
  const float* b_ih0 = (const float*)d_in[3];
  const float* b_hh0 = (const float*)d_in[4];
  const float* w_ih1 = (const float*)d_in[5];
  const float* w_hh1 = (const float*)d_in[6];
  const float* b_ih1 = (const float*)d_in[7];
  const float* b_hh1 = (const float*)d_in[8];
  const float* w_lin = (const float*)d_in[9];
  const float* b_lin = (const float*)d_in[10];
  float* out = (float*)d_out;

  unsigned char* ws = (unsigned char*)d_ws;
  unsigned* h0g   = (unsigned*)ws;                      // ring: [4][65536] u32 = 1 MB
  unsigned* h1g   = (unsigned*)(ws + (1 << 20));        // [2][65536] u32 = 512 KB
  unsigned* flags = (unsigned*)(ws + (1536 << 10));     // [32 groups][32] u32
  // memset(0): h zeros (bf16 0x0000 = h[-1]) + flags = 0
  hipMemsetAsync(d_ws, 0, (1536 << 10) + 4096, stream);

  size_t lds_bytes = (size_t)(2 * BT) * KP * 2     // h0s + h1s
                   + (size_t)(BT * XS) * 4         // x preload
                   + (size_t)(Pz * Hz) * 4;        // w_lin (head)
  hipFuncSetAttribute((const void*)lstm2,
                      hipFuncAttributeMaxDynamicSharedMemorySize, (int)lds_bytes);
  lstm2<<<2 * GB * GS, 256, lds_bytes, stream>>>(x, w_ih0, w_hh0, b_ih0, b_hh0,
                                                 w_ih1, w_hh1, b_ih1, b_hh1,
                                                 w_lin, b_lin, out, h0g, h1g, flags);
}

// Round 10
// 822.213 us; speedup vs baseline: 1.3359x; 1.0455x over previous
//
#include <hip/hip_runtime.h>

// Problem constants
constexpr int Bz = 512;   // batch
constexpr int Tz = 256;   // seq len
constexpr int Hz = 256;   // hidden
constexpr int Pz = 14;    // predict dim
constexpr int GB = 32;    // batch groups
constexpr int GS = 8;     // hidden slices per group
constexpr int BT = 16;    // batch per group (512/32)
constexpr int KP = 264;   // LDS h row stride (shorts)
constexpr int XS = 260;   // x LDS row stride (floats)
constexpr int HBsz = BT * KP;   // shorts per h stage buffer

typedef short s8v __attribute__((ext_vector_type(8)));
typedef float f4v __attribute__((ext_vector_type(4)));
typedef unsigned long long u64;

__device__ __forceinline__ short f2bf(float f) {
  unsigned u = __float_as_uint(f);
  u = (u + 0x7fffu + ((u >> 16) & 1u)) >> 16;   // RNE
  return (short)u;
}
__device__ __forceinline__ float bf2f(short s) {
  return __uint_as_float(((unsigned)(unsigned short)s) << 16);
}
// Fast gates (R11/R14-proven numerics)
__device__ __forceinline__ float sigm(float v) {
  return __builtin_amdgcn_rcpf(1.0f + __builtin_amdgcn_exp2f(-1.442695041f * v));
}
__device__ __forceinline__ float tanh_f(float v) {
  return 1.0f - 2.0f * __builtin_amdgcn_rcpf(__builtin_amdgcn_exp2f(2.885390082f * v) + 1.0f);
}

__device__ __forceinline__ u64 llc_load64(const u64* p) {
  return __hip_atomic_load(p, __ATOMIC_RELAXED, __HIP_MEMORY_SCOPE_AGENT);
}
__device__ __forceinline__ void llc_store64(u64* p, u64 v) {
  __hip_atomic_store(p, v, __ATOMIC_RELAXED, __HIP_MEMORY_SCOPE_AGENT);
}

// R19 = R14's proven data layout + compute with the FLAG HANDSHAKE REPLACED
// by a 1-BIT IN-BAND GENERATION TAG (fixing R10's two measured defects:
// 2x word volume and s_sleep(1) retry hammering).
//
// Tag: slot s&1 alternates generations g = s>>1. gbit(i) = ((i>>1)&1)^1 is
// embedded as bit0 of pk1's low bf16 (ONE h1 unit of 256 perturbed by
// <= 1 ulp bf16 -- below existing rounding noise). memset(0) has bit 0,
// and gbit makes iteration 0's expectation (slot 1, bit 0) match init;
// thereafter each slot's bit alternates 1,0,1,0 -- no collision with init.
//
// Consumer iteration i: load its 8 u64 words of slot (i-1)&1; accept word
// when bit == (i==0 ? 0 : gbit(i-1)); retry ONLY missed words with
// s_sleep(8) (~0.2us) backoff. Volume = R14's stage exactly; no flags, no
// flag-poll RT, no barrier-A, no F-barrier, no store drain.
//
// Safety (R10's induction, which PASSED on hardware): a producer stores
// gen-g words only after its stage verified ALL gen-(g-1) words, which
// exist only after every block stored gen-g-1, which (data dependence:
// loads -> LDS -> MFMA -> store) follows that block's gen-g-2 stage loads
// RETURNING. Hence when a slot is overwritten, every reader of the old
// generation has finished (WAR), and verified-bit => whole u64 current
// (8B single-copy atomic via __hip_atomic_store/load) (RAW).
// Intra-block: LDS staging double-buffered by parity (R17-proven layout);
// sync1 is the ONLY barrier per step. Self-loads racing own stores just
// cost one retry (self-correcting).
__global__ void __launch_bounds__(256, 1)
lstm2(const float* __restrict__ x,
      const float* __restrict__ w_ih0, const float* __restrict__ w_hh0,
      const float* __restrict__ b_ih0, const float* __restrict__ b_hh0,
      const float* __restrict__ w_ih1, const float* __restrict__ w_hh1,
      const float* __restrict__ b_ih1, const float* __restrict__ b_hh1,
      const float* __restrict__ w_lin, const float* __restrict__ b_lin,
      float* __restrict__ out,
      u64* __restrict__ hg)
{
  const int blk  = blockIdx.x;
  const int g    = blk >> 3;      // batch group (32)
  const int sl   = blk & 7;       // hidden slice (8)
  const int tid  = threadIdx.x;
  const int w    = tid >> 6;      // wave
  const int lane = tid & 63;
  const int q    = lane >> 4;
  const int l15  = lane & 15;     // batch within group
  const int gbase = g * BT;

  extern __shared__ char smem_raw[];
  short* hstage = (short*)smem_raw;             // [2 parities][h0|h1][BT][KP]
  float* xls = (float*)(hstage + 4 * HBsz);     // [BT][XS] x preload
  float* wls = xls + BT * XS;                   // [Pz][256] w_lin kpos order

  // ---- one-time: weights -> register A-fragments (permuted k gather) ----
  // kpos = sl*32 + w*8 + q*2 + j  <->  k_true = sl*32 + w*4 + q + 16*j
  s8v Wf[3][2][8];   // [mat: hh0, ih1, hh1][mti][kt]
  {
    const float* wsrc[3] = {w_hh0, w_ih1, w_hh1};
    #pragma unroll
    for (int mat = 0; mat < 3; ++mat) {
      #pragma unroll
      for (int mti = 0; mti < 2; ++mti) {
        int rr = (w + mti * 4) * 16 + l15;          // rr = unit*4+gate
        int grow = (rr & 3) * Hz + sl * 32 + (rr >> 2);
        const float* p = wsrc[mat] + (size_t)grow * Hz;
        #pragma unroll
        for (int kt = 0; kt < 8; ++kt) {
          s8v f;
          #pragma unroll
          for (int j = 0; j < 8; ++j) {
            int ktrue = kt * 32 + q * 4 + (j >> 1) + 16 * (j & 1);
            f[j] = f2bf(p[ktrue]);
          }
          Wf[mat][mti][kt] = f;
        }
      }
    }
  }
  // per-lane epilogue constants: units uA = w*4+q, uB = 16+uA; gates r=0..3
  const int uA = w * 4 + q, uB = 16 + w * 4 + q;
  float wihA[4], wihB[4], b0A[4], b0B[4], b1A[4], b1B[4];
  #pragma unroll
  for (int r = 0; r < 4; ++r) {
    int ga_ = r * Hz + sl * 32 + uA;
    int gb_ = r * Hz + sl * 32 + uB;
    wihA[r] = w_ih0[ga_];              wihB[r] = w_ih0[gb_];
    b0A[r]  = b_ih0[ga_] + b_hh0[ga_]; b0B[r]  = b_ih0[gb_] + b_hh0[gb_];
    b1A[r]  = b_ih1[ga_] + b_hh1[ga_]; b1B[r]  = b_ih1[gb_] + b_hh1[gb_];
  }
  float c0A = 0.f, c0B = 0.f, c1A = 0.f, c1B = 0.f;   // cell states in VGPRs

  // ---- preload x (this group's 16 batches) and permuted w_lin (head) ----
  for (int i = tid; i < BT * (Tz / 4); i += 256) {
    int b = i >> 6, c4 = i & 63;
    f4v v = *(const f4v*)(x + (size_t)(gbase + b) * Tz + c4 * 4);
    *(f4v*)(xls + b * XS + c4 * 4) = v;
  }
  if (sl == 0) {
    for (int i = tid; i < Pz * Hz; i += 256) {
      int p = i >> 8, kpos = i & 255;
      int sl2 = kpos >> 5, w2 = (kpos >> 3) & 3, q2 = (kpos >> 1) & 3, jj = kpos & 1;
      wls[i] = w_lin[p * Hz + sl2 * 32 + w2 * 4 + q2 + 16 * jj];
    }
  }
  __syncthreads();   // prologue LDS (x, wls) visible

  // per-thread stage decode (R9-proven): i -> (c, b, slw); two u64s per k
  size_t gidx[8];
  int ldo[4];
  #pragma unroll
  for (int k = 0; k < 4; ++k) {
    int i = tid + k * 256;
    int c = i & 1, b = (i >> 1) & 15, slw = i >> 5;
    gidx[2 * k]     = ((size_t)slw * Bz + gbase + b) * 4 + 2 * c;
    gidx[2 * k + 1] = gidx[2 * k] + 1;
    ldo[k] = b * KP + slw * 8 + c * 4;
  }
  const size_t stbase = (size_t)(sl * 4 + w) * 2048 + (size_t)(gbase + l15) * 4 + q;

  for (int s = 0; s <= Tz; ++s) {
    // ---- A/B: tagged stage: load 8 u64 of slot (s-1)&1, verify bit, retry ----
    const u64* sp = hg + (size_t)((s + 1) & 1) * 65536;
    const unsigned expb = (s == 0) ? 0u : ((((unsigned)(s - 1) >> 1) & 1u) ^ 1u);
    u64 v[8];
    #pragma unroll
    for (int j = 0; j < 8; ++j) v[j] = llc_load64(sp + gidx[j]);
    for (;;) {
      unsigned miss = 0;
      #pragma unroll
      for (int j = 0; j < 8; ++j)
        if ((unsigned)((v[j] >> 32) & 1u) != expb) miss |= 1u << j;
      if (!miss) break;
      __builtin_amdgcn_s_sleep(8);
      #pragma unroll
      for (int j = 0; j < 8; ++j)
        if (miss & (1u << j)) v[j] = llc_load64(sp + gidx[j]);
    }
    // extract to double-buffered LDS (parity s&1): lo32 pair -> h0, hi32 -> h1
    short* hb0 = hstage + (s & 1) * (2 * HBsz);
    short* hb1 = hb0 + HBsz;
    #pragma unroll
    for (int k = 0; k < 4; ++k) {
      u64 lo = v[2 * k], hi = v[2 * k + 1];
      *(u64*)(hb0 + ldo[k]) = (u64)(unsigned)lo | ((u64)(unsigned)hi << 32);
      *(u64*)(hb1 + ldo[k]) = (lo >> 32) | ((hi >> 32) << 32);
    }
    __syncthreads();   // sync1: staged LDS visible (ONLY barrier per step)

    // ---- C: fused MFMA (L0: 16, L1: 32); weights from regs; 16 b128 reads ----
    f4v a0A = {0.f,0.f,0.f,0.f}, a0B = {0.f,0.f,0.f,0.f};
    f4v a1A = {0.f,0.f,0.f,0.f}, a1B = {0.f,0.f,0.f,0.f};
    const short* H0f = hb0 + l15 * KP + q * 8;
    const short* H1f = hb1 + l15 * KP + q * 8;
    #pragma unroll
    for (int kt = 0; kt < 8; ++kt) {
      s8v h0v = *(const s8v*)(H0f + kt * 32);
      s8v h1v = *(const s8v*)(H1f + kt * 32);
      a0A = __builtin_amdgcn_mfma_f32_16x16x32_bf16(Wf[0][0][kt], h0v, a0A, 0, 0, 0);
      a0B = __builtin_amdgcn_mfma_f32_16x16x32_bf16(Wf[0][1][kt], h0v, a0B, 0, 0, 0);
      a1A = __builtin_amdgcn_mfma_f32_16x16x32_bf16(Wf[1][0][kt], h0v, a1A, 0, 0, 0);
      a1B = __builtin_amdgcn_mfma_f32_16x16x32_bf16(Wf[1][1][kt], h0v, a1B, 0, 0, 0);
      a1A = __builtin_amdgcn_mfma_f32_16x16x32_bf16(Wf[2][0][kt], h1v, a1A, 0, 0, 0);
      a1B = __builtin_amdgcn_mfma_f32_16x16x32_bf16(Wf[2][1][kt], h1v, a1B, 0, 0, 0);
    }

    // ---- D: in-register epilogues -> one packed u32 per layer ----
    unsigned pk0 = 0, pk1 = 0;
    if (s < Tz) {
      float xv = xls[l15 * XS + s];
      float iA = sigm  (a0A[0] + xv * wihA[0] + b0A[0]);
      float fA = sigm  (a0A[1] + xv * wihA[1] + b0A[1]);
      float gA = tanh_f(a0A[2] + xv * wihA[2] + b0A[2]);
      float oA = sigm  (a0A[3] + xv * wihA[3] + b0A[3]);
      c0A = fA * c0A + iA * gA;
      float iB = sigm  (a0B[0] + xv * wihB[0] + b0B[0]);
      float fB = sigm  (a0B[1] + xv * wihB[1] + b0B[1]);
      float gB = tanh_f(a0B[2] + xv * wihB[2] + b0B[2]);
      float oB = sigm  (a0B[3] + xv * wihB[3] + b0B[3]);
      c0B = fB * c0B + iB * gB;
      pk0 = (unsigned)(unsigned short)f2bf(oA * tanh_f(c0A))
          | ((unsigned)(unsigned short)f2bf(oB * tanh_f(c0B)) << 16);
    }
    if (s >= 1) {
      float iA = sigm  (a1A[0] + b1A[0]);
      float fA = sigm  (a1A[1] + b1A[1]);
      float gA = tanh_f(a1A[2] + b1A[2]);
      float oA = sigm  (a1A[3] + b1A[3]);
      c1A = fA * c1A + iA * gA;
      float iB = sigm  (a1B[0] + b1B[0]);
      float fB = sigm  (a1B[1] + b1B[1]);
      float gB = tanh_f(a1B[2] + b1B[2]);
      float oB = sigm  (a1B[3] + b1B[3]);
      c1B = fB * c1B + iB * gB;
      pk1 = (unsigned)(unsigned short)f2bf(oA * tanh_f(c1A))
          | ((unsigned)(unsigned short)f2bf(oB * tanh_f(c1B)) << 16);
    }
    // inject generation tag into pk1 bit0 (one h1 unit, <=1 ulp bf16)
    pk1 = (pk1 & ~1u) | ((((unsigned)s >> 1) & 1u) ^ 1u);

    // ---- E: ONE combined fire-and-forget store (no drain, no flag) ----
    llc_store64(hg + (size_t)(s & 1) * 65536 + stbase,
                (u64)pk0 | ((u64)pk1 << 32));
  }

  // ---- final head (sl==0 blocks): out = h1[Tz-1] @ w_lin^T + b_lin ----
  // words of iteration Tz live at slot 0 with gbit(Tz) = ((Tz>>1)&1)^1 = 1.
  if (sl == 0) {
    const u64* sp = hg + (size_t)(Tz & 1) * 65536;
    const unsigned expb = (((unsigned)Tz >> 1) & 1u) ^ 1u;
    u64 v[8];
    #pragma unroll
    for (int j = 0; j < 8; ++j) v[j] = llc_load64(sp + gidx[j]);
    for (;;) {
      unsigned miss = 0;
      #pragma unroll
      for (int j = 0; j < 8; ++j)
        if ((unsigned)((v[j] >> 32) & 1u) != expb) miss |= 1u << j;
      if (!miss) break;
      __builtin_amdgcn_s_sleep(8);
      #pragma unroll
      for (int j = 0; j < 8; ++j)
        if (miss & (1u << j)) v[j] = llc_load64(sp + gidx[j]);
    }
    // stage h1 (hi32 halves) into parity-0 h0 region; all waves long past
    // reading it (loop ended at sync1(Tz)+compute) -- barrier below anyway
    short* hb = hstage;   // parity 0, h0 region
    #pragma unroll
    for (int k = 0; k < 4; ++k) {
      u64 lo = v[2 * k], hi = v[2 * k + 1];
      *(u64*)(hb + ldo[k]) = (lo >> 32) | ((hi >> 32) << 32);
    }
    __syncthreads();
    for (int i = tid; i < BT * Pz; i += 256) {
      int b = i / Pz, p = i - b * Pz;
      const float* wr = wls + p * Hz;
      float acc = b_lin[p];
      for (int kk = 0; kk < Hz; ++kk)
        acc += bf2f(hb[b * KP + kk]) * wr[kk];   // both in kpos order
      out[(gbase + b) * Pz + p] = acc;
    }
  }
}

extern "C" void kernel_launch(void* const* d_in, const int* in_sizes, int n_in,
                              void* d_out, int out_size, void* d_ws, size_t ws_size,
                              hipStream_t stream) {
  const float* x     = (const float*)d_in[0];
  const float* w_ih0 = (const float*)d_in[1];
  const float* w_hh0 = (const float*)d_in[2];
  const float* b_ih0 = (const float*)d_in[3];
  const float* b_hh0 = (const float*)d_in[4];
  const float* w_ih1 = (const float*)d_in[5];
  const float* w_hh1 = (const float*)d_in[6];
  const float* b_ih1 = (const float*)d_in[7];
  const float* b_hh1 = (const float*)d_in[8];
  const float* w_lin = (const float*)d_in[9];
  const float* b_lin = (const float*)d_in[10];
  float* out = (float*)d_out;

  u64* hg = (u64*)d_ws;   // [2][65536] u64 (512 KB/parity)
  // memset(0): payload zeros (= h[-1], h[-2]) AND tag bit 0 (= "initial
  // generation", matched by iteration 0's expected bit). No flags at all.
  hipMemsetAsync(d_ws, 0, 1 << 20, stream);

  size_t lds_bytes = (size_t)(4 * HBsz) * 2        // h staging, double-buffered
                   + (size_t)(BT * XS) * 4         // x preload
                   + (size_t)(Pz * Hz) * 4;        // permuted w_lin (head)
  hipFuncSetAttribute((const void*)lstm2,
                      hipFuncAttributeMaxDynamicSharedMemorySize, (int)lds_bytes);
  lstm2<<<GB * GS, 256, lds_bytes, stream>>>(x, w_ih0, w_hh0, b_ih0, b_hh0,
                                             w_ih1, w_hh1, b_ih1, b_hh1,
                                             w_lin, b_lin, out, hg);
}